// Round 1
// baseline (923.502 us; speedup 1.0000x reference)
//
#include <hip/hip_runtime.h>
#include <hip/hip_bf16.h>
#include <math.h>

#define N_NODES 25000
#define N_EDGES 400000

__device__ __forceinline__ float sigmoidf_(float a){ return 1.f/(1.f+expf(-a)); }
__device__ __forceinline__ float siluf_(float a){ return a/(1.f+expf(-a)); }
__device__ __forceinline__ unsigned short f2bf(float f){
  unsigned int x = __float_as_uint(f);
  x += 0x7FFFu + ((x>>16)&1u);
  return (unsigned short)(x>>16);
}
__device__ __forceinline__ float bf2f(unsigned short u){
  return __uint_as_float(((unsigned int)u)<<16);
}

// ---------------- K1: node precompute: s1, v1, sc_s, sc_v ----------------
__global__ __launch_bounds__(256) void k_node_pre(
    const float* __restrict__ x, const float* __restrict__ z,
    const float* __restrict__ W1s, const float* __restrict__ Wscs,
    const float* __restrict__ W1v, const float* __restrict__ Wscv,
    float* __restrict__ s1, float* __restrict__ v1,
    float* __restrict__ scs, float* __restrict__ scv)
{
  int n = blockIdx.x;
  __shared__ float sx[160];
  int t = threadIdx.x;
  if (t < 160) sx[t] = x[(size_t)n*160 + t];
  __syncthreads();
  float zz = z[n];
  for (int j = t; j < 352; j += 256) {
    if (j < 64) {
      float a = 0.f;
      #pragma unroll
      for (int k = 0; k < 64; ++k) a = fmaf(sx[k], W1s[k*64 + j], a);
      s1[(size_t)n*64 + j] = a * zz * 0.125f;
    } else if (j < 160) {
      int jj = j - 64;
      float a = 0.f;
      #pragma unroll
      for (int k = 0; k < 64; ++k) a = fmaf(sx[k], Wscs[k*96 + jj], a);
      scs[(size_t)n*96 + jj] = a * zz * 0.125f;
    } else if (j < 256) {
      int p = j - 160; int w = p/3, c = p - w*3;
      float a = 0.f;
      #pragma unroll
      for (int u = 0; u < 32; ++u) a = fmaf(sx[64 + u*3 + c], W1v[u*32 + w], a);
      v1[(size_t)n*96 + p] = a * zz * 0.17677669529663687f;
    } else {
      int p = j - 256; int w = p/3, c = p - w*3;
      float a = 0.f;
      #pragma unroll
      for (int u = 0; u < 32; ++u) a = fmaf(sx[64 + u*3 + c], Wscv[u*32 + w], a);
      scv[(size_t)n*96 + p] = a * zz * 0.17677669529663687f;
    }
  }
}

// ---------------- K2: histogram of edge_dst ----------------
__global__ __launch_bounds__(256) void k_hist(const int* __restrict__ dst, int* __restrict__ cnt){
  int e = blockIdx.x*256 + threadIdx.x;
  if (e < N_EDGES) atomicAdd(&cnt[dst[e]], 1);
}

// ---------------- K3: exclusive scan (single block) ----------------
__global__ __launch_bounds__(1024) void k_scan(const int* __restrict__ cnt, int* __restrict__ offs, int* __restrict__ cursor){
  __shared__ int ts[1024];
  int t = threadIdx.x;
  const int per = 25; // ceil(25000/1024)
  int lo = t*per, hi = min(lo+per, N_NODES);
  int s = 0;
  for (int i = lo; i < hi; ++i) s += cnt[i];
  ts[t] = s;
  __syncthreads();
  for (int off = 1; off < 1024; off <<= 1) {
    int v = 0;
    if (t >= off) v = ts[t-off];
    __syncthreads();
    if (t >= off) ts[t] += v;
    __syncthreads();
  }
  int run = ts[t] - s; // exclusive prefix
  for (int i = lo; i < hi; ++i) { offs[i] = run; cursor[i] = run; run += cnt[i]; }
  if (hi == N_NODES && lo < N_NODES) offs[N_NODES] = run;
}

// ---------------- K4: scatter edge ids to sorted positions ----------------
__global__ __launch_bounds__(256) void k_scatter(const int* __restrict__ src, const int* __restrict__ dst,
    int* __restrict__ cursor, int* __restrict__ perm, int* __restrict__ srcs){
  int e = blockIdx.x*256 + threadIdx.x;
  if (e < N_EDGES) {
    int d = dst[e];
    int p = atomicAdd(&cursor[d], 1);
    perm[p] = e;
    srcs[p] = src[e];
  }
}

// ---------------- K5: edge MLP GEMM, 64 edges/tile, w stored bf16 ----------------
__global__ __launch_bounds__(256) void k_edge_gemm(
    const int* __restrict__ perm,
    const float* __restrict__ es,     // E x 12
    const float* __restrict__ Wr1,    // 12 x 100
    const float* __restrict__ Wr2,    // 100 x 224
    unsigned short* __restrict__ wbuf)
{
  __shared__ int pm[64];
  __shared__ float esm[64*13];
  __shared__ __align__(16) float hs[100*64];
  int t = threadIdx.x;
  int p0 = blockIdx.x * 64;
  if (t < 64) pm[t] = perm[p0 + t];
  __syncthreads();
  for (int i = t; i < 64*12; i += 256) {
    int e = i / 12, k = i - e*12;
    esm[e*13 + k] = es[(size_t)pm[e]*12 + k];
  }
  __syncthreads();
  for (int idx = t; idx < 64*100; idx += 256) {
    int e = idx & 63, kh = idx >> 6;
    float a = 0.f;
    #pragma unroll
    for (int kk = 0; kk < 12; ++kk) a = fmaf(esm[e*13+kk], Wr1[kk*100 + kh], a);
    a *= 0.28867513459481287f;
    hs[kh*64 + e] = a / (1.f + expf(-a));   // silu
  }
  __syncthreads();
  int tc = t & 31, tr = t >> 5;
  float acc[8][7];
  #pragma unroll
  for (int i=0;i<8;i++)
    #pragma unroll
    for (int m=0;m<7;m++) acc[i][m] = 0.f;
  const float* wr2p = Wr2 + tc;
  for (int k = 0; k < 100; ++k) {
    float4 h0 = *reinterpret_cast<const float4*>(&hs[k*64 + tr*8]);
    float4 h1 = *reinterpret_cast<const float4*>(&hs[k*64 + tr*8 + 4]);
    float hv[8] = {h0.x,h0.y,h0.z,h0.w,h1.x,h1.y,h1.z,h1.w};
    float wv[7];
    #pragma unroll
    for (int m=0;m<7;m++) wv[m] = wr2p[k*224 + 32*m];
    #pragma unroll
    for (int i=0;i<8;i++){
      #pragma unroll
      for (int m=0;m<7;m++) acc[i][m] = fmaf(hv[i], wv[m], acc[i][m]);
    }
  }
  #pragma unroll
  for (int i=0;i<8;i++){
    int p = p0 + tr*8 + i;
    unsigned short* wp = wbuf + (size_t)p*224 + tc;
    #pragma unroll
    for (int m=0;m<7;m++) wp[32*m] = f2bf(acc[i][m]*0.1f);
  }
}

// ---------------- K6: per-node gather, message form, aggregate, output ----------------
__global__ __launch_bounds__(256) void k_node_out(
    const int* __restrict__ offs, const int* __restrict__ perm, const int* __restrict__ srcs,
    const unsigned short* __restrict__ wbuf,
    const float* __restrict__ s1, const float* __restrict__ v1,
    const float* __restrict__ scs, const float* __restrict__ scv,
    const float* __restrict__ eattr, const float* __restrict__ z,
    const float* __restrict__ W2s, const float* __restrict__ W2v,
    float* __restrict__ out)
{
  __shared__ __align__(16) float stg[4*392];
  __shared__ float ns[96];
  __shared__ float nv[384];
  __shared__ float ys[96];
  int n = blockIdx.x;
  int t = threadIdx.x;
  int lo = offs[n], hi = offs[n+1];
  float a0=0.f, a1=0.f, a2=0.f;
  for (int p = lo; p < hi; p += 4) {
    int cnt = min(4, hi - p);
    for (int i = t; i < cnt*97; i += 256) {
      int slot = i / 97, q = i - slot*97;
      float4 val;
      if (q < 56) {
        const ushort4 u = *reinterpret_cast<const ushort4*>(wbuf + (size_t)(p+slot)*224 + q*4);
        val.x = bf2f(u.x); val.y = bf2f(u.y); val.z = bf2f(u.z); val.w = bf2f(u.w);
      } else if (q < 72) {
        int src = srcs[p+slot];
        val = *reinterpret_cast<const float4*>(s1 + (size_t)src*64 + (q-56)*4);
      } else if (q < 96) {
        int src = srcs[p+slot];
        val = *reinterpret_cast<const float4*>(v1 + (size_t)src*96 + (q-72)*4);
      } else {
        int e = perm[p+slot];
        val = *reinterpret_cast<const float4*>(eattr + (size_t)e*4);
      }
      *reinterpret_cast<float4*>(&stg[slot*392 + q*4]) = val;
    }
    __syncthreads();
    for (int s = 0; s < cnt; ++s) {
      const float* st = &stg[s*392];
      float se = st[384], ve0 = st[385], ve1 = st[386], ve2 = st[387];
      if (t < 64) {                   // m1a rows 0..63
        float m = st[64+t] * st[224+t];
        a0 = fmaf(m, ve0, a0); a1 = fmaf(m, ve1, a1); a2 = fmaf(m, ve2, a2);
      } else if (t < 96) {            // m1b rows 64..95
        int uu = t-64;
        float w3 = st[128+uu]*se;
        a0 = fmaf(w3, st[288+uu*3+0], a0);
        a1 = fmaf(w3, st[288+uu*3+1], a1);
        a2 = fmaf(w3, st[288+uu*3+2], a2);
      } else if (t < 128) {           // m1c rows 96..127 (cross product)
        int uu = t-96;
        float w5 = st[192+uu]*0.7071067811865476f;
        float b0 = st[288+uu*3+0], b1 = st[288+uu*3+1], b2 = st[288+uu*3+2];
        a0 = fmaf(w5, b1*ve2 - b2*ve1, a0);
        a1 = fmaf(w5, b2*ve0 - b0*ve2, a1);
        a2 = fmaf(w5, b0*ve1 - b1*ve0, a2);
      } else if (t < 192) {           // m0a scalars 0..63
        int j = t-128;
        a0 = fmaf(st[j]*st[224+j], se, a0);
      } else if (t < 224) {           // m0b scalars 64..95
        int j2 = t-192;
        float d = st[288+j2*3]*ve0 + st[288+j2*3+1]*ve1 + st[288+j2*3+2]*ve2;
        a0 = fmaf(st[160+j2]*0.5773502691896258f, d, a0);
      }
    }
    __syncthreads();
  }
  float zz = z[n];
  float sc = 0.25f * zz;              // / sqrt(16) and * z
  if (t < 128) { nv[t*3+0]=a0*sc; nv[t*3+1]=a1*sc; nv[t*3+2]=a2*sc; }
  else if (t < 224) ns[t-128] = a0*sc;
  __syncthreads();
  if (t < 96) {
    float a = 0.f;
    #pragma unroll
    for (int k = 0; k < 96; ++k) a = fmaf(ns[k], W2s[k*96+t], a);
    a *= 0.10206207261596575f;
    ys[t] = 0.3826834323650898f * scs[(size_t)n*96+t] + 0.9238795325112867f * a;
  }
  float yv = 0.f;
  int idx = t - 96;
  if (t >= 96 && t < 192) {
    int w = idx/3, c = idx - w*3;
    float a = 0.f;
    #pragma unroll
    for (int u = 0; u < 128; ++u) a = fmaf(nv[u*3+c], W2v[u*32+w], a);
    a *= 0.08838834764831845f;
    yv = 0.3826834323650898f * scv[(size_t)n*96+idx] + 0.9238795325112867f * a;
  }
  __syncthreads();
  if (t < 64) out[(size_t)n*160 + t] = siluf_(ys[t]);
  if (t >= 96 && t < 192) {
    int w = idx/3;
    out[(size_t)n*160 + 64 + idx] = yv * sigmoidf_(ys[64+w]);
  }
}

extern "C" void kernel_launch(void* const* d_in, const int* in_sizes, int n_in,
                              void* d_out, int out_size, void* d_ws, size_t ws_size,
                              hipStream_t stream)
{
  const float* x     = (const float*)d_in[0];
  const float* z     = (const float*)d_in[1];
  const int*   esrc  = (const int*)d_in[2];
  const int*   edst  = (const int*)d_in[3];
  const float* eattr = (const float*)d_in[4];
  const float* escal = (const float*)d_in[5];
  const float* Wscs  = (const float*)d_in[6];
  const float* Wscv  = (const float*)d_in[7];
  const float* W1s   = (const float*)d_in[8];
  const float* W1v   = (const float*)d_in[9];
  const float* Wr1   = (const float*)d_in[10];
  const float* Wr2   = (const float*)d_in[11];
  const float* W2s   = (const float*)d_in[12];
  const float* W2v   = (const float*)d_in[13];
  float* out = (float*)d_out;

  char* ws = (char*)d_ws;
  size_t off = 0;
  auto alloc = [&](size_t bytes)->char* {
    char* p = ws + off;
    off = (off + bytes + 255) & ~(size_t)255;
    return p;
  };
  float* s1   = (float*)alloc((size_t)N_NODES*64*4);
  float* v1   = (float*)alloc((size_t)N_NODES*96*4);
  float* scs  = (float*)alloc((size_t)N_NODES*96*4);
  float* scv  = (float*)alloc((size_t)N_NODES*96*4);
  unsigned short* wbuf = (unsigned short*)alloc((size_t)N_EDGES*224*2);
  int* cnt    = (int*)alloc((size_t)N_NODES*4);
  int* offs   = (int*)alloc((size_t)(N_NODES+1)*4);
  int* cursor = (int*)alloc((size_t)N_NODES*4);
  int* perm   = (int*)alloc((size_t)N_EDGES*4);
  int* srcs   = (int*)alloc((size_t)N_EDGES*4);

  hipMemsetAsync(cnt, 0, (size_t)N_NODES*4, stream);
  k_node_pre<<<N_NODES, 256, 0, stream>>>(x, z, W1s, Wscs, W1v, Wscv, s1, v1, scs, scv);
  k_hist<<<(N_EDGES+255)/256, 256, 0, stream>>>(edst, cnt);
  k_scan<<<1, 1024, 0, stream>>>(cnt, offs, cursor);
  k_scatter<<<(N_EDGES+255)/256, 256, 0, stream>>>(esrc, edst, cursor, perm, srcs);
  k_edge_gemm<<<N_EDGES/64, 256, 0, stream>>>(perm, escal, Wr1, Wr2, wbuf);
  k_node_out<<<N_NODES, 256, 0, stream>>>(offs, perm, srcs, wbuf, s1, v1, scs, scv, eattr, z, W2s, W2v, out);
}

// Round 2
// 616.939 us; speedup vs baseline: 1.4969x; 1.4969x over previous
//
#include <hip/hip_runtime.h>
#include <hip/hip_bf16.h>
#include <math.h>

#define N_NODES 25000
#define N_EDGES 400000

typedef short bf16x8 __attribute__((ext_vector_type(8)));
typedef float f32x4 __attribute__((ext_vector_type(4)));

__device__ __forceinline__ float sigmoidf_(float a){ return 1.f/(1.f+__expf(-a)); }
__device__ __forceinline__ float siluf_(float a){ return a/(1.f+__expf(-a)); }
__device__ __forceinline__ unsigned short f2bf(float f){
  unsigned int x = __float_as_uint(f);
  x += 0x7FFFu + ((x>>16)&1u);
  return (unsigned short)(x>>16);
}
__device__ __forceinline__ float bf2f(unsigned short u){
  return __uint_as_float(((unsigned int)u)<<16);
}

// ---------------- K1: node precompute: s1, v1, sc_s, sc_v ----------------
__global__ __launch_bounds__(256) void k_node_pre(
    const float* __restrict__ x, const float* __restrict__ z,
    const float* __restrict__ W1s, const float* __restrict__ Wscs,
    const float* __restrict__ W1v, const float* __restrict__ Wscv,
    float* __restrict__ s1, float* __restrict__ v1,
    float* __restrict__ scs, float* __restrict__ scv)
{
  int n = blockIdx.x;
  __shared__ float sx[160];
  int t = threadIdx.x;
  if (t < 160) sx[t] = x[(size_t)n*160 + t];
  __syncthreads();
  float zz = z[n];
  for (int j = t; j < 352; j += 256) {
    if (j < 64) {
      float a = 0.f;
      #pragma unroll
      for (int k = 0; k < 64; ++k) a = fmaf(sx[k], W1s[k*64 + j], a);
      s1[(size_t)n*64 + j] = a * zz * 0.125f;
    } else if (j < 160) {
      int jj = j - 64;
      float a = 0.f;
      #pragma unroll
      for (int k = 0; k < 64; ++k) a = fmaf(sx[k], Wscs[k*96 + jj], a);
      scs[(size_t)n*96 + jj] = a * zz * 0.125f;
    } else if (j < 256) {
      int p = j - 160; int w = p/3, c = p - w*3;
      float a = 0.f;
      #pragma unroll
      for (int u = 0; u < 32; ++u) a = fmaf(sx[64 + u*3 + c], W1v[u*32 + w], a);
      v1[(size_t)n*96 + p] = a * zz * 0.17677669529663687f;
    } else {
      int p = j - 256; int w = p/3, c = p - w*3;
      float a = 0.f;
      #pragma unroll
      for (int u = 0; u < 32; ++u) a = fmaf(sx[64 + u*3 + c], Wscv[u*32 + w], a);
      scv[(size_t)n*96 + p] = a * zz * 0.17677669529663687f;
    }
  }
}

// ---------------- K2: histogram of edge_dst ----------------
__global__ __launch_bounds__(256) void k_hist(const int* __restrict__ dst, int* __restrict__ cnt){
  int e = blockIdx.x*256 + threadIdx.x;
  if (e < N_EDGES) atomicAdd(&cnt[dst[e]], 1);
}

// ---------------- K3: exclusive scan (single block) ----------------
__global__ __launch_bounds__(1024) void k_scan(const int* __restrict__ cnt, int* __restrict__ offs, int* __restrict__ cursor){
  __shared__ int ts[1024];
  int t = threadIdx.x;
  const int per = 25;
  int lo = t*per, hi = min(lo+per, N_NODES);
  int s = 0;
  for (int i = lo; i < hi; ++i) s += cnt[i];
  ts[t] = s;
  __syncthreads();
  for (int off = 1; off < 1024; off <<= 1) {
    int v = 0;
    if (t >= off) v = ts[t-off];
    __syncthreads();
    if (t >= off) ts[t] += v;
    __syncthreads();
  }
  int run = ts[t] - s;
  for (int i = lo; i < hi; ++i) { offs[i] = run; cursor[i] = run; run += cnt[i]; }
  if (hi == N_NODES && lo < N_NODES) offs[N_NODES] = run;
}

// ---------------- K4: scatter edge ids to sorted positions ----------------
__global__ __launch_bounds__(256) void k_scatter(const int* __restrict__ src, const int* __restrict__ dst,
    int* __restrict__ cursor, int* __restrict__ perm, int* __restrict__ srcs){
  int e = blockIdx.x*256 + threadIdx.x;
  if (e < N_EDGES) {
    int d = dst[e];
    int p = atomicAdd(&cursor[d], 1);
    perm[p] = e;
    srcs[p] = src[e];
  }
}

// ---------------- K4b: repack Wr2 -> bf16 B-fragment layout ----------------
// Wr2bf[((nt*4+ks)*64 + lane)*8 + j] = Wr2[k*224 + n], k = ks*32+(lane>>4)*8+j (0 if k>=100), n = nt*16+(lane&15)
__global__ __launch_bounds__(256) void k_prep(const float* __restrict__ Wr2, unsigned short* __restrict__ Wr2bf){
  int i = blockIdx.x*256 + threadIdx.x;
  if (i < 28672) {
    int j = i & 7, lane = (i>>3)&63, ks = (i>>9)&3, nt = i>>11;
    int k = ks*32 + (lane>>4)*8 + j;
    int n = nt*16 + (lane&15);
    float v = (k < 100) ? Wr2[k*224 + n] : 0.f;
    Wr2bf[i] = f2bf(v);
  }
}

// ---------------- K5: edge MLP via MFMA, 64 edges/block ----------------
__global__ __launch_bounds__(256) void k_edge_gemm(
    const int* __restrict__ perm,
    const float* __restrict__ es,
    const float* __restrict__ Wr1,
    const unsigned short* __restrict__ Wr2bf,
    unsigned short* __restrict__ wbuf)
{
  __shared__ int pm[64];
  __shared__ float esm[64*13];
  __shared__ __align__(16) unsigned short hs[64*136];  // 64 edges x 128 K (bf16), +8 pad
  int t = threadIdx.x;
  int p0 = blockIdx.x * 64;
  if (t < 64) pm[t] = perm[p0 + t];
  // zero K-pad columns 100..127
  for (int i = t; i < 64*28; i += 256) {
    int e = i/28, c = i - (i/28)*28;
    hs[e*136 + 100 + c] = 0;
  }
  __syncthreads();
  for (int i = t; i < 768; i += 256) {
    int e = i/12, k = i - (i/12)*12;
    esm[e*13 + k] = es[(size_t)pm[e]*12 + k];
  }
  __syncthreads();
  // h = silu(es @ Wr1 / sqrt(12)), bf16 into LDS
  for (int idx = t; idx < 6400; idx += 256) {
    int e = idx & 63, kh = idx >> 6;
    float a = 0.f;
    #pragma unroll
    for (int kk = 0; kk < 12; ++kk) a = fmaf(esm[e*13+kk], Wr1[kk*100 + kh], a);
    a *= 0.28867513459481287f;
    float h = a / (1.f + __expf(-a));
    hs[e*136 + kh] = f2bf(h);
  }
  __syncthreads();
  // MFMA: [64x128] x [128x224], waves as 2M x 2N
  int l = t & 63, wid = t >> 6;
  int mrow = wid >> 1, ng = wid & 1;
  int r16 = l & 15, khi = l >> 4;
  f32x4 acc[2][7];
  #pragma unroll
  for (int i=0;i<2;i++)
    #pragma unroll
    for (int j=0;j<7;j++) acc[i][j] = (f32x4){0.f,0.f,0.f,0.f};
  #pragma unroll
  for (int ks = 0; ks < 4; ++ks) {
    bf16x8 a0 = *(const bf16x8*)&hs[(mrow*32 + r16)*136 + ks*32 + khi*8];
    bf16x8 a1 = *(const bf16x8*)&hs[(mrow*32 + 16 + r16)*136 + ks*32 + khi*8];
    #pragma unroll
    for (int ni = 0; ni < 7; ++ni) {
      int nt = ng*7 + ni;
      bf16x8 b = *(const bf16x8*)&Wr2bf[(size_t)((nt*4+ks)*64 + l)*8];
      acc[0][ni] = __builtin_amdgcn_mfma_f32_16x16x32_bf16(a0, b, acc[0][ni], 0, 0, 0);
      acc[1][ni] = __builtin_amdgcn_mfma_f32_16x16x32_bf16(a1, b, acc[1][ni], 0, 0, 0);
    }
  }
  // D: col = lane&15, row = (lane>>4)*4 + reg
  int rowb = p0 + mrow*32 + khi*4;
  int colb = ng*112 + r16;
  #pragma unroll
  for (int mi=0;mi<2;mi++)
    #pragma unroll
    for (int ni=0;ni<7;ni++)
      #pragma unroll
      for (int r=0;r<4;r++)
        wbuf[(size_t)(rowb + mi*16 + r)*224 + colb + ni*16] = f2bf(acc[mi][ni][r]*0.1f);
}

// ---------------- K6: wave-per-node gather + aggregate + output ----------------
__global__ __launch_bounds__(256) void k_node_out(
    const int* __restrict__ offs, const int* __restrict__ perm, const int* __restrict__ srcs,
    const unsigned short* __restrict__ wbuf,
    const float* __restrict__ s1, const float* __restrict__ v1,
    const float* __restrict__ scs, const float* __restrict__ scv,
    const float* __restrict__ eattr, const float* __restrict__ z,
    const float* __restrict__ W2s, const float* __restrict__ W2v,
    float* __restrict__ out)
{
  __shared__ float bns[4][96];
  __shared__ float bnv[4][384];
  __shared__ float ysl[4][96];
  __shared__ float yvl[4][96];
  int t = threadIdx.x;
  int wid = t >> 6, l = t & 63, l31 = l & 31;
  int n = blockIdx.x*4 + wid;
  int lo = offs[n], hi = offs[n+1];
  float accS = 0.f, accS2 = 0.f;
  float aV0=0.f,aV1=0.f,aV2=0.f, aX0=0.f,aX1=0.f,aX2=0.f;
  #pragma unroll 2
  for (int p = lo; p < hi; ++p) {
    const unsigned short* wr = wbuf + (size_t)p*224;
    int e = perm[p];
    int src = srcs[p];
    float4 ea = *reinterpret_cast<const float4*>(eattr + (size_t)e*4);
    float w1 = bf2f(wr[l]);
    float w2 = bf2f(wr[64+l]);
    float ss = s1[(size_t)src*64 + l];
    const float* vp = v1 + (size_t)src*96 + l31*3;
    float b0 = vp[0], b1 = vp[1], b2 = vp[2];
    float se = ea.x, e0 = ea.y, e1 = ea.z, e2 = ea.w;
    accS = fmaf(w1*ss, se, accS);                       // m0a, s-feature l
    float m = w2*ss;                                    // m1a, v-feature l
    aV0 = fmaf(m, e0, aV0); aV1 = fmaf(m, e1, aV1); aV2 = fmaf(m, e2, aV2);
    if (l < 32) {
      float w3 = bf2f(wr[128+l31]);
      float w4 = bf2f(wr[160+l31]);
      accS2 = fmaf(w4, b0*e0 + b1*e1 + b2*e2, accS2);   // m0b, s-feature 64+l
      float tt = w3*se;                                 // m1b, v-feature 64+l
      aX0 = fmaf(tt, b0, aX0); aX1 = fmaf(tt, b1, aX1); aX2 = fmaf(tt, b2, aX2);
    } else {
      float w5 = bf2f(wr[192+l31]);                     // m1c, v-feature 96+l31
      aX0 = fmaf(w5, b1*e2 - b2*e1, aX0);
      aX1 = fmaf(w5, b2*e0 - b0*e2, aX1);
      aX2 = fmaf(w5, b0*e1 - b1*e0, aX2);
    }
  }
  float sc = 0.25f * z[n];
  bns[wid][l] = accS * sc;
  bnv[wid][l*3+0] = aV0*sc; bnv[wid][l*3+1] = aV1*sc; bnv[wid][l*3+2] = aV2*sc;
  if (l < 32) {
    bns[wid][64+l] = accS2 * sc * 0.5773502691896258f;
    bnv[wid][(64+l)*3+0] = aX0*sc; bnv[wid][(64+l)*3+1] = aX1*sc; bnv[wid][(64+l)*3+2] = aX2*sc;
  } else {
    float s2 = sc * 0.7071067811865476f;
    bnv[wid][(96+l31)*3+0] = aX0*s2; bnv[wid][(96+l31)*3+1] = aX1*s2; bnv[wid][(96+l31)*3+2] = aX2*s2;
  }
  __syncthreads();
  // ys = c_s*scs + c_x*(ns @ W2s)/sqrt(96)
  for (int task = t; task < 384; task += 256) {
    int nd = task / 96, r = task - (task/96)*96;
    int nn = blockIdx.x*4 + nd;
    float a = 0.f;
    #pragma unroll 4
    for (int k = 0; k < 96; ++k) a = fmaf(bns[nd][k], W2s[k*96 + r], a);
    ysl[nd][r] = 0.3826834323650898f * scs[(size_t)nn*96 + r] + 0.09429304f * a;
  }
  // yv = c_s*scv + c_x*(nv @ W2v)/sqrt(128)
  for (int task = t; task < 384; task += 256) {
    int nd = task / 96, idx = task - (task/96)*96;
    int nn = blockIdx.x*4 + nd;
    int w = idx/3, c = idx - w*3;
    float a = 0.f;
    #pragma unroll 4
    for (int u = 0; u < 128; ++u) a = fmaf(bnv[nd][u*3 + c], W2v[u*32 + w], a);
    yvl[nd][idx] = 0.3826834323650898f * scv[(size_t)nn*96 + idx] + 0.08166018f * a;
  }
  __syncthreads();
  for (int task = t; task < 256; task += 256) {
    int nd = task >> 6, r = task & 63;
    int nn = blockIdx.x*4 + nd;
    out[(size_t)nn*160 + r] = siluf_(ysl[nd][r]);
  }
  for (int task = t; task < 384; task += 256) {
    int nd = task / 96, idx = task - (task/96)*96;
    int nn = blockIdx.x*4 + nd;
    int w = idx/3;
    out[(size_t)nn*160 + 64 + idx] = yvl[nd][idx] * sigmoidf_(ysl[nd][64+w]);
  }
}

extern "C" void kernel_launch(void* const* d_in, const int* in_sizes, int n_in,
                              void* d_out, int out_size, void* d_ws, size_t ws_size,
                              hipStream_t stream)
{
  const float* x     = (const float*)d_in[0];
  const float* z     = (const float*)d_in[1];
  const int*   esrc  = (const int*)d_in[2];
  const int*   edst  = (const int*)d_in[3];
  const float* eattr = (const float*)d_in[4];
  const float* escal = (const float*)d_in[5];
  const float* Wscs  = (const float*)d_in[6];
  const float* Wscv  = (const float*)d_in[7];
  const float* W1s   = (const float*)d_in[8];
  const float* W1v   = (const float*)d_in[9];
  const float* Wr1   = (const float*)d_in[10];
  const float* Wr2   = (const float*)d_in[11];
  const float* W2s   = (const float*)d_in[12];
  const float* W2v   = (const float*)d_in[13];
  float* out = (float*)d_out;

  char* ws = (char*)d_ws;
  size_t off = 0;
  auto alloc = [&](size_t bytes)->char* {
    char* p = ws + off;
    off = (off + bytes + 255) & ~(size_t)255;
    return p;
  };
  float* s1   = (float*)alloc((size_t)N_NODES*64*4);
  float* v1   = (float*)alloc((size_t)N_NODES*96*4);
  float* scs  = (float*)alloc((size_t)N_NODES*96*4);
  float* scv  = (float*)alloc((size_t)N_NODES*96*4);
  unsigned short* wbuf = (unsigned short*)alloc((size_t)N_EDGES*224*2);
  int* cnt    = (int*)alloc((size_t)N_NODES*4);
  int* offs   = (int*)alloc((size_t)(N_NODES+1)*4);
  int* cursor = (int*)alloc((size_t)N_NODES*4);
  int* perm   = (int*)alloc((size_t)N_EDGES*4);
  int* srcs   = (int*)alloc((size_t)N_EDGES*4);
  unsigned short* Wr2bf = (unsigned short*)alloc((size_t)28672*2);

  hipMemsetAsync(cnt, 0, (size_t)N_NODES*4, stream);
  k_prep<<<112, 256, 0, stream>>>(Wr2, Wr2bf);
  k_node_pre<<<N_NODES, 256, 0, stream>>>(x, z, W1s, Wscs, W1v, Wscv, s1, v1, scs, scv);
  k_hist<<<(N_EDGES+255)/256, 256, 0, stream>>>(edst, cnt);
  k_scan<<<1, 1024, 0, stream>>>(cnt, offs, cursor);
  k_scatter<<<(N_EDGES+255)/256, 256, 0, stream>>>(esrc, edst, cursor, perm, srcs);
  k_edge_gemm<<<N_EDGES/64, 256, 0, stream>>>(perm, escal, Wr1, Wr2bf, wbuf);
  k_node_out<<<N_NODES/4, 256, 0, stream>>>(offs, perm, srcs, wbuf, s1, v1, scs, scv, eattr, z, W2s, W2v, out);
}